// Round 1
// baseline (95.586 us; speedup 1.0000x reference)
//
#include <hip/hip_runtime.h>
#include <math.h>

// Problem constants (from reference setup_inputs):
// B=256 graphs, A=64 atoms, E=128 edges, K=6 neighbors, H=256 channels.
#define NB 256
#define NA 64
#define NE 128
#define NK 6
#define NH 256

// Edges per block: 4 waves x 4 edges. 8 blocks cover one b.
#define EPB 16
#define BLOCKS_PER_B (NE / EPB)          // 8
#define NWG (NB * BLOCKS_PER_B)          // 2048

// No rep staging in LDS: the per-b slice is 128 KiB and L2-resident (4 MiB/XCD),
// and each row is reused only ~6x. Staging it cost 134 KB LDS -> 1 block/CU ->
// 1 wave/SIMD, which cannot hide HBM latency. Instead: tiny LDS (weights +
// neighbor indices), 2048 blocks (~8/CU, 32 waves/CU), gathers straight from
// global through L2. XCD-chunked swizzle keeps all 8 blocks of a b on one XCD
// so each 128 KiB slice is fetched from HBM exactly once.
__global__ __launch_bounds__(256, 4) void edge_msg_kernel(
    const float* __restrict__ rep,   // [B,E,H]
    const int*   __restrict__ pairs, // [B,E,2]
    const int*   __restrict__ nbrs,  // [B,E,K]
    const float* __restrict__ xyz,   // [B,A,3]
    float*       __restrict__ out)   // [B,E,H]
{
    __shared__ float s_w[NE];          // all E weights for this b (neighbors span all E)
    __shared__ int   s_nb[EPB * NK];   // this block's neighbor indices

    // Bijective XCD-chunked swizzle (NWG % 8 == 0): physical p -> logical so
    // that XCD x = p%8 owns logical range [x*256, (x+1)*256) = b in [x*32,(x+1)*32).
    const int p       = blockIdx.x;
    const int logical = (p & 7) * (NWG / 8) + (p >> 3);
    const int b       = logical >> 3;        // / BLOCKS_PER_B
    const int chunk   = logical & (BLOCKS_PER_B - 1);
    const int e0      = chunk * EPB;

    const int tid = threadIdx.x;

    // --- per-edge distance weights for ALL edges of b (threads 0..127) ---
    if (tid < NE) {
        const int p0 = pairs[(b * NE + tid) * 2 + 0];
        const int p1 = pairs[(b * NE + tid) * 2 + 1];
        const float* x0 = xyz + ((size_t)b * NA + p0) * 3;
        const float* x1 = xyz + ((size_t)b * NA + p1) * 3;
        const float dx = x0[0] - x1[0];
        const float dy = x0[1] - x1[1];
        const float dz = x0[2] - x1[2];
        const float d2 = dx * dx + dy * dy + dz * dz;
        float inv = 1.0f / d2;          // IEEE divide: matches XLA
        if (isinf(inv)) inv = 0.0f;     // jnp.where(isinf(inv), 0, inv)
        s_w[tid] = inv;
    }

    // --- stage this block's neighbor indices (96 ints) ---
    if (tid < EPB * NK) {
        s_nb[tid] = nbrs[((size_t)b * NE + e0) * NK + tid];
    }
    __syncthreads();

    // --- compute: wave w handles local edges [w*4, w*4+4) ---
    const int wid  = tid >> 6;
    const int lane = tid & 63;           // float4 index within H

    const float4* rep4 = (const float4*)(rep + (size_t)b * NE * NH);
    float4*       out4 = (float4*)(out + (size_t)b * NE * NH);

#pragma unroll
    for (int ei = 0; ei < EPB / 4; ++ei) {
        const int e = wid * (EPB / 4) + ei;   // local edge index in [0,16)
        float4 acc = make_float4(0.f, 0.f, 0.f, 0.f);
#pragma unroll
        for (int k = 0; k < NK; ++k) {
            const int   nb = s_nb[e * NK + k];          // wave-uniform -> broadcast
            const float w  = s_w[nb];                   // broadcast
            const float4 v = rep4[nb * (NH / 4) + lane]; // 1 KiB coalesced, L2-hit
            acc.x += w * v.x;
            acc.y += w * v.y;
            acc.z += w * v.z;
            acc.w += w * v.w;
        }
        out4[(size_t)(e0 + e) * (NH / 4) + lane] = acc;
    }
}

extern "C" void kernel_launch(void* const* d_in, const int* in_sizes, int n_in,
                              void* d_out, int out_size, void* d_ws, size_t ws_size,
                              hipStream_t stream) {
    const float* rep   = (const float*)d_in[0]; // [1,B,E,H] fp32
    const int*   pairs = (const int*)  d_in[1]; // [B,E,2]
    const int*   nbrs  = (const int*)  d_in[2]; // [B,E,K]
    const float* xyz   = (const float*)d_in[3]; // [B,A,3]
    float*       out   = (float*)d_out;         // [1,B,E,H]

    edge_msg_kernel<<<dim3(NWG), dim3(256), 0, stream>>>(rep, pairs, nbrs, xyz, out);
}